// Round 7
// baseline (501.915 us; speedup 1.0000x reference)
//
#include <hip/hip_runtime.h>
#include <stdint.h>

// Binarized dense: C[r][u] = sum_k sign(x[r][k]) * sign(W[k][u]) + b[u]
//   sign(v) = +1 if v >= 0 else -1   -> bit(v) = (v < 0)
//   dot = F - 2 * popcount(xbits ^ wbits)
//
// Packed layout per row/col (F=4096 bits = 64 u64 words):
//   u64 word w = c'*4 + j, c' = 256-float chunk, j = float4 component;
//   bit i of word = bit(v[c'*256 + i*4 + j])  (i = lane of the ballot).
// pack_w reproduces this mapping bit-exactly (verified rounds 1/3/4/5).
//
// Fused kernel (round-5 structure, VGPR cap fixed): block = 64 rows x 512
// cols, K chunked 8 x 512 floats, LDS double-buffered. Per chunk: issue
// next-chunk global loads into regs -> compute current chunk -> ballot/
// ds_write the in-flight data -> one barrier. x is read from HBM exactly
// once; the ~27 us popcount VALU work hides under the 268 MB HBM stream.
//
// __launch_bounds__(512, 1): under either 2nd-arg semantics (1 block/CU or
// 1 wave/EU) the register allocator may use 256 VGPRs. Round 5 used (512,2)
// which capped at 128 VGPRs -> ~190-reg demand spilled (FETCH 564 MB, WRITE
// 887 MB of scratch). Demand ~190 fits under 256: no spill.

#define BATCH  16384
#define INF    4096
#define UNITS  512
#define KW     128      // u32 words per row (4096/32)
#define KW64   64       // u64 words per row
#define ROWS   64       // x rows per block
#define KC     16       // u32 words per K-chunk (512 floats)
#define NCH    8        // chunks (8*16 = 128 words)
#define PAD    20       // LDS row stride in u32 (5 x 16B granules, odd -> spread)

// ---------------- pack W: [4096,512] f32 -> [512,64] u64 --------------------
__global__ __launch_bounds__(256) void pack_w_kernel(const float* __restrict__ W,
                                                     unsigned long long* __restrict__ Wp) {
    int t  = blockIdx.x * 256 + threadIdx.x;   // 0..32767
    int u  = t & 511;                          // column
    int cj = t >> 9;                           // 0..63 = c*4 + j
    int j  = cj & 3;
    int c  = cj >> 2;
    const float* base = W + (size_t)(c * 256 + j) * UNITS + u;
    unsigned long long m = 0;
    #pragma unroll 16
    for (int i = 0; i < 64; ++i) {
        float v = base[(size_t)(4 * i) * UNITS];
        m |= (unsigned long long)(v < 0.f) << i;
    }
    Wp[(size_t)u * KW64 + cj] = m;
}

// ------------------------------ fused kernel --------------------------------
__global__ __launch_bounds__(512, 1) void fused_kernel(const float* __restrict__ x,
                                                       const uint32_t* __restrict__ Wp,
                                                       const float* __restrict__ bias,
                                                       float* __restrict__ C) {
    __shared__ uint32_t sX[2][ROWS][PAD];    // 10 KB
    __shared__ uint32_t sW[2][UNITS][PAD];   // 80 KB
    const int t  = threadIdx.x;
    const int w  = t >> 6;      // wave 0..7 (packs rows w*8..w*8+7)
    const int l  = t & 63;
    const int tx = t & 31;      // output cols tx + 32j, j = 0..15
    const int ty = t >> 5;      // output rows ty + 16i, i = 0..3
    const int row0 = blockIdx.x * ROWS;

    int acc[4][16] = {};

    // ---- prologue: pack chunk 0, stage W chunk 0 (synchronous) ----
    #pragma unroll
    for (int rr = 0; rr < 8; ++rr) {
        const float4* src = reinterpret_cast<const float4*>(
            x + (size_t)(row0 + w * 8 + rr) * INF);
        #pragma unroll
        for (int h = 0; h < 2; ++h) {
            float4 v = src[h * 64 + l];
            unsigned long long b0 = __ballot(v.x < 0.f);
            unsigned long long b1 = __ballot(v.y < 0.f);
            unsigned long long b2 = __ballot(v.z < 0.f);
            unsigned long long b3 = __ballot(v.w < 0.f);
            if (l == 0) {
                uint64_t* d = reinterpret_cast<uint64_t*>(&sX[0][w * 8 + rr][h * 8]);
                d[0] = b0; d[1] = b1; d[2] = b2; d[3] = b3;
            }
        }
    }
    #pragma unroll
    for (int i = 0; i < 4; ++i) {
        int idx = t + 512 * i;             // 0..2047 uint4
        int row = idx >> 2, c4 = idx & 3;
        uint4 v = reinterpret_cast<const uint4*>(Wp + (size_t)row * KW)[c4];
        *reinterpret_cast<uint4*>(&sW[0][row][c4 * 4]) = v;
    }
    __syncthreads();

    for (int c = 0; c < NCH; ++c) {
        const int cur = c & 1;
        const bool pf = (c + 1 < NCH);

        // ---- phase A: issue prefetch loads for chunk c+1 (stay in flight) ----
        float4 xr[16];
        uint4  wr[4];
        if (pf) {
            #pragma unroll
            for (int rr = 0; rr < 8; ++rr) {
                const float4* src = reinterpret_cast<const float4*>(
                    x + (size_t)(row0 + w * 8 + rr) * INF + (size_t)(c + 1) * 512);
                xr[rr * 2]     = src[l];
                xr[rr * 2 + 1] = src[64 + l];
            }
            #pragma unroll
            for (int i = 0; i < 4; ++i) {
                int idx = t + 512 * i;
                int row = idx >> 2, c4 = idx & 3;
                wr[i] = reinterpret_cast<const uint4*>(
                    Wp + (size_t)row * KW + (c + 1) * KC)[c4];
            }
        }

        // ---- phase B: compute chunk c from LDS[cur] ----
        #pragma unroll
        for (int k4 = 0; k4 < KC / 4; ++k4) {
            uint4 xv[4];
            #pragma unroll
            for (int i = 0; i < 4; ++i)
                xv[i] = *reinterpret_cast<const uint4*>(&sX[cur][ty + 16 * i][k4 * 4]);
            #pragma unroll
            for (int j = 0; j < 16; ++j) {
                uint4 wv = *reinterpret_cast<const uint4*>(&sW[cur][tx + 32 * j][k4 * 4]);
                #pragma unroll
                for (int i = 0; i < 4; ++i) {
                    acc[i][j] += __popc(xv[i].x ^ wv.x);
                    acc[i][j] += __popc(xv[i].y ^ wv.y);
                    acc[i][j] += __popc(xv[i].z ^ wv.z);
                    acc[i][j] += __popc(xv[i].w ^ wv.w);
                }
            }
        }

        // ---- phase C: consume prefetch into buffer cur^1 ----
        if (pf) {
            #pragma unroll
            for (int rr = 0; rr < 8; ++rr) {
                #pragma unroll
                for (int h = 0; h < 2; ++h) {
                    float4 v = xr[rr * 2 + h];
                    unsigned long long b0 = __ballot(v.x < 0.f);
                    unsigned long long b1 = __ballot(v.y < 0.f);
                    unsigned long long b2 = __ballot(v.z < 0.f);
                    unsigned long long b3 = __ballot(v.w < 0.f);
                    if (l == 0) {
                        uint64_t* d = reinterpret_cast<uint64_t*>(
                            &sX[cur ^ 1][w * 8 + rr][h * 8]);
                        d[0] = b0; d[1] = b1; d[2] = b2; d[3] = b3;
                    }
                }
            }
            #pragma unroll
            for (int i = 0; i < 4; ++i) {
                int idx = t + 512 * i;
                int row = idx >> 2, c4 = idx & 3;
                *reinterpret_cast<uint4*>(&sW[cur ^ 1][row][c4 * 4]) = wr[i];
            }
        }
        __syncthreads();
    }

    // ---- epilogue: C = INF - 2*acc + bias ----
    #pragma unroll
    for (int j = 0; j < 16; ++j) {
        int u = tx + 32 * j;
        float bj = bias[u];
        #pragma unroll
        for (int i = 0; i < 4; ++i) {
            int r = row0 + ty + 16 * i;
            C[(size_t)r * UNITS + u] = (float)(INF - 2 * acc[i][j]) + bj;
        }
    }
}

extern "C" void kernel_launch(void* const* d_in, const int* in_sizes, int n_in,
                              void* d_out, int out_size, void* d_ws, size_t ws_size,
                              hipStream_t stream) {
    const float* x = (const float*)d_in[0];
    const float* W = (const float*)d_in[1];
    const float* b = (const float*)d_in[2];
    float* out = (float*)d_out;

    unsigned long long* Wp = (unsigned long long*)d_ws;   // 256 KB

    pack_w_kernel<<<32768 / 256, 256, 0, stream>>>(W, Wp);
    fused_kernel<<<BATCH / ROWS, 512, 0, stream>>>(
        x, (const uint32_t*)Wp, b, out);
}

// Round 8
// 140.840 us; speedup vs baseline: 3.5637x; 3.5637x over previous
//
#include <hip/hip_runtime.h>
#include <stdint.h>

// Binarized dense: C[r][u] = sum_k sign(x[r][k]) * sign(W[k][u]) + b[u]
//   sign(v) = +1 if v >= 0 else -1   -> bit(v) = (v < 0)
//   dot = F - 2 * popcount(xbits ^ wbits)
//
// Packed layout per row/col (F=4096 bits = 128 u32 words):
//   u64 word w = c*4 + j, c = 0..15 (256-float chunk), j = 0..3 (float4 comp);
//   bit i of word = bit(v[c*256 + i*4 + j]) (i = ballot lane). u32 view:
//   u64 word w occupies u32 indices 2w (lo), 2w+1 (hi).
// pack_w reproduces this mapping bit-exactly (verified rounds 1/3/4/5/7).
//
// Fused kernel: 256 blocks x 512 threads; block = 64 rows x 512 cols; x read
// from HBM exactly once. K chunked 16 x 256 floats (KC=8 u32 words), LDS
// double-buffered. Per chunk: A) stage W chunk (transient regs -> LDS) and
// ISSUE x loads for c+1; B) popcount-GEMM chunk c from LDS; C) ballot-pack
// the in-flight x into buffer^1; one barrier.
//
// Register budget engineered for the 128-VGPR cap the allocator insists on
// for 512-thread blocks (rounds 5/7: VGPR_Count=128 + scratch spills):
//   acc packed 2xu16 per u32: 32 | xr in-flight: 32 | xv: 32 | wv: 8 | addr ~14
//   => ~118 < 128, no spill. u16 halves exact: each sum <= 4096 < 65536.

#define BATCH  16384
#define INF    4096
#define UNITS  512
#define KW     128      // u32 words per row (4096/32)
#define KW64   64       // u64 words per row
#define ROWS   64       // x rows per block
#define KC     8        // u32 words per K-chunk (256 floats)
#define NCH    16       // chunks
#define SXW    12       // sX row stride (48 B: 16B-aligned for b128, 8B for b64)
#define SWW    9        // sW row stride (gcd(9,32)=1 -> b32 reads 2-way = free)

// ---------------- pack W: [4096,512] f32 -> [512,64] u64 --------------------
__global__ __launch_bounds__(256) void pack_w_kernel(const float* __restrict__ W,
                                                     unsigned long long* __restrict__ Wp) {
    int t  = blockIdx.x * 256 + threadIdx.x;   // 0..32767
    int u  = t & 511;                          // column
    int cj = t >> 9;                           // 0..63 = c*4 + j
    int j  = cj & 3;
    int c  = cj >> 2;
    const float* base = W + (size_t)(c * 256 + j) * UNITS + u;
    unsigned long long m = 0;
    #pragma unroll 16
    for (int i = 0; i < 64; ++i) {
        float v = base[(size_t)(4 * i) * UNITS];
        m |= (unsigned long long)(v < 0.f) << i;
    }
    Wp[(size_t)u * KW64 + cj] = m;
}

// ------------------------------ fused kernel --------------------------------
__global__ __launch_bounds__(512, 1) void fused_kernel(const float* __restrict__ x,
                                                       const uint32_t* __restrict__ Wp,
                                                       const float* __restrict__ bias,
                                                       float* __restrict__ C) {
    __shared__ __attribute__((aligned(16))) uint32_t sX[2][ROWS][SXW];   //  6 KB
    __shared__ __attribute__((aligned(16))) uint32_t sW[2][UNITS][SWW];  // 36.9 KB
    const int t = threadIdx.x;
    const int w = t >> 6;       // wave 0..7: owns rows w*8..w*8+7 (pack+compute)
    const int l = t & 63;       // lane; also output col base (cols l + 64j)
    const int row0 = blockIdx.x * ROWS;
    const float4* xf4 = reinterpret_cast<const float4*>(x);

    uint32_t acc[8][4] = {};    // acc[i][j2]: lo16 = col l+128*j2, hi16 = +64

    // ---- prologue: stage chunk 0 (W + packed x) ----
    {
        uint4 w0 = *reinterpret_cast<const uint4*>(
            Wp + (size_t)(t >> 1) * KW + (t & 1) * 4);
        uint4 w1 = *reinterpret_cast<const uint4*>(
            Wp + ((size_t)(t >> 1) + 256) * KW + (t & 1) * 4);
        uint32_t* d = &sW[0][t >> 1][(t & 1) * 4];
        d[0] = w0.x; d[1] = w0.y; d[2] = w0.z; d[3] = w0.w;
        d = &sW[0][(t >> 1) + 256][(t & 1) * 4];
        d[0] = w1.x; d[1] = w1.y; d[2] = w1.z; d[3] = w1.w;
        #pragma unroll
        for (int rr = 0; rr < 8; ++rr) {
            float4 v = xf4[((size_t)(row0 + w * 8 + rr) << 10) + l];
            unsigned long long b0 = __ballot(v.x < 0.f);
            unsigned long long b1 = __ballot(v.y < 0.f);
            unsigned long long b2 = __ballot(v.z < 0.f);
            unsigned long long b3 = __ballot(v.w < 0.f);
            if (l < 4) {
                unsigned long long bb = l == 0 ? b0 : l == 1 ? b1 : l == 2 ? b2 : b3;
                *reinterpret_cast<unsigned long long*>(&sX[0][w * 8 + rr][l * 2]) = bb;
            }
        }
        __syncthreads();
    }

    for (int c = 0; c < NCH; ++c) {
        const int cb = c & 1, nb = cb ^ 1;
        const bool pf = (c + 1 < NCH);
        float4 xr[8];

        // ---- A: stage next W chunk now; issue next x loads (stay in flight) ----
        if (pf) {
            const uint32_t* wsrc = Wp + (c + 1) * KC;
            uint4 w0 = *reinterpret_cast<const uint4*>(
                wsrc + (size_t)(t >> 1) * KW + (t & 1) * 4);
            uint4 w1 = *reinterpret_cast<const uint4*>(
                wsrc + ((size_t)(t >> 1) + 256) * KW + (t & 1) * 4);
            #pragma unroll
            for (int rr = 0; rr < 8; ++rr)
                xr[rr] = xf4[((size_t)(row0 + w * 8 + rr) << 10) + (c + 1) * 64 + l];
            uint32_t* d = &sW[nb][t >> 1][(t & 1) * 4];
            d[0] = w0.x; d[1] = w0.y; d[2] = w0.z; d[3] = w0.w;
            d = &sW[nb][(t >> 1) + 256][(t & 1) * 4];
            d[0] = w1.x; d[1] = w1.y; d[2] = w1.z; d[3] = w1.w;
        }

        // ---- B: popcount-GEMM chunk c ----
        #pragma unroll
        for (int k4 = 0; k4 < 2; ++k4) {
            uint4 xv[8];
            #pragma unroll
            for (int i = 0; i < 8; ++i)
                xv[i] = *reinterpret_cast<const uint4*>(&sX[cb][w * 8 + i][k4 * 4]);
            #pragma unroll
            for (int j2 = 0; j2 < 4; ++j2) {
                const uint32_t* p0 = &sW[cb][l + 128 * j2][k4 * 4];
                const uint32_t* p1 = &sW[cb][l + 128 * j2 + 64][k4 * 4];
                uint32_t a0 = p0[0], a1 = p0[1], a2 = p0[2], a3 = p0[3];
                uint32_t b0 = p1[0], b1 = p1[1], b2 = p1[2], b3 = p1[3];
                #pragma unroll
                for (int i = 0; i < 8; ++i) {
                    uint32_t c0 = __popc(xv[i].x ^ a0) + __popc(xv[i].y ^ a1)
                                + __popc(xv[i].z ^ a2) + __popc(xv[i].w ^ a3);
                    uint32_t c1 = __popc(xv[i].x ^ b0) + __popc(xv[i].y ^ b1)
                                + __popc(xv[i].z ^ b2) + __popc(xv[i].w ^ b3);
                    acc[i][j2] += c0 + (c1 << 16);
                }
            }
        }

        // ---- C: ballot-pack the in-flight x into buffer nb ----
        if (pf) {
            #pragma unroll
            for (int rr = 0; rr < 8; ++rr) {
                float4 v = xr[rr];
                unsigned long long b0 = __ballot(v.x < 0.f);
                unsigned long long b1 = __ballot(v.y < 0.f);
                unsigned long long b2 = __ballot(v.z < 0.f);
                unsigned long long b3 = __ballot(v.w < 0.f);
                if (l < 4) {
                    unsigned long long bb = l == 0 ? b0 : l == 1 ? b1 : l == 2 ? b2 : b3;
                    *reinterpret_cast<unsigned long long*>(&sX[nb][w * 8 + rr][l * 2]) = bb;
                }
            }
        }
        __syncthreads();
    }

    // ---- epilogue: unpack u16 halves, C = INF - 2*acc + bias ----
    #pragma unroll
    for (int j2 = 0; j2 < 4; ++j2) {
        int u0 = l + 128 * j2, u1 = u0 + 64;
        float bv0 = bias[u0], bv1 = bias[u1];
        #pragma unroll
        for (int i = 0; i < 8; ++i) {
            size_t r = (size_t)(row0 + w * 8 + i) * UNITS;
            uint32_t pk = acc[i][j2];
            C[r + u0] = (float)(INF - 2 * (int)(pk & 0xFFFFu)) + bv0;
            C[r + u1] = (float)(INF - 2 * (int)(pk >> 16)) + bv1;
        }
    }
}

extern "C" void kernel_launch(void* const* d_in, const int* in_sizes, int n_in,
                              void* d_out, int out_size, void* d_ws, size_t ws_size,
                              hipStream_t stream) {
    const float* x = (const float*)d_in[0];
    const float* W = (const float*)d_in[1];
    const float* b = (const float*)d_in[2];
    float* out = (float*)d_out;

    unsigned long long* Wp = (unsigned long long*)d_ws;   // 256 KB

    pack_w_kernel<<<32768 / 256, 256, 0, stream>>>(W, Wp);
    fused_kernel<<<BATCH / ROWS, 512, 0, stream>>>(
        x, (const uint32_t*)Wp, b, out);
}

// Round 9
// 99.594 us; speedup vs baseline: 5.0396x; 1.4141x over previous
//
#include <hip/hip_runtime.h>
#include <stdint.h>

// Binarized dense: C[r][u] = sum_k sign(x[r][k]) * sign(W[k][u]) + b[u]
//   sign(v) = +1 if v >= 0 else -1   -> bit(v) = (v < 0)
//   dot = F - 2 * popcount(xbits ^ wbits)
//
// Packed layout per row/col (F=4096 bits = 128 u32 words):
//   u64 word w = c*4 + j, c = chunk, j = float4 comp; bit i = ballot lane i.
//   u32 view: u64 word w at indices 2w (lo), 2w+1 (hi). With KC=8 u32/chunk,
//   chunk-local u32 word order = b0.lo,b0.hi,b1.lo,b1.hi,b2.lo,b2.hi,b3.lo,b3.hi.
// pack_w reproduces this mapping bit-exactly (verified rounds 1/3/4/5/7/8).
//
// Fused kernel v3: 512 blocks x 512 threads, block = 32 rows x 512 cols,
// 2 blocks/CU (LDS = sW only, 48 KB). x-bits are held as WAVE-UNIFORM SGPRs
// (the __ballot results) -- no sX, no x LDS traffic, xor is v_xor_b32 v,s,v.
// Per chunk: A) issue next W loads (L2) then next x loads (HBM, stay in
// flight); B) popcount-GEMM from sW[cb] b128 reads (stride-12 rows: 48l mod
// 128 covers all eight 16B windows -> conflict-free); C) ds_write W[nb],
// ballot-pack x; one barrier. x read from HBM exactly once.

#define BATCH  16384
#define INF    4096
#define UNITS  512
#define KW     128      // u32 words per row (4096/32)
#define KW64   64       // u64 words per row
#define ROWSB  32       // x rows per block
#define KC     8        // u32 words per K-chunk (256 floats)
#define NCH    16       // chunks
#define SWW    12       // sW row stride in u32 (48 B: 16B-aligned, conflict-free)

// ---------------- pack W: [4096,512] f32 -> [512,64] u64 --------------------
__global__ __launch_bounds__(256) void pack_w_kernel(const float* __restrict__ W,
                                                     unsigned long long* __restrict__ Wp) {
    int t  = blockIdx.x * 256 + threadIdx.x;   // 0..32767
    int u  = t & 511;                          // column
    int cj = t >> 9;                           // 0..63 = c*4 + j
    int j  = cj & 3;
    int c  = cj >> 2;
    const float* base = W + (size_t)(c * 256 + j) * UNITS + u;
    unsigned long long m = 0;
    #pragma unroll 16
    for (int i = 0; i < 64; ++i) {
        float v = base[(size_t)(4 * i) * UNITS];
        m |= (unsigned long long)(v < 0.f) << i;
    }
    Wp[(size_t)u * KW64 + cj] = m;
}

// ------------------------------ fused kernel --------------------------------
__global__ __launch_bounds__(512) void fused_kernel(const float* __restrict__ x,
                                                    const uint32_t* __restrict__ Wp,
                                                    const float* __restrict__ bias,
                                                    float* __restrict__ C) {
    __shared__ __attribute__((aligned(16))) uint32_t sW[2][UNITS][SWW];  // 48 KB
    const int t = threadIdx.x;
    const int w = t >> 6;       // wave 0..7: owns rows w*4 .. w*4+3
    const int l = t & 63;       // lane; output cols l + 64*{0..7}
    const int row0 = blockIdx.x * ROWSB;
    const float4* xf4 = reinterpret_cast<const float4*>(x);
    const int wrow = t >> 1;            // W staging row (this thread)
    const int wcol = (t & 1) * 4;       // W staging word offset

    uint32_t acc[4][4] = {};    // acc[i][j2]: lo16 = col l+128*j2, hi16 = +64
    unsigned long long xb[4][4];        // wave-uniform ballots (SGPRs)

    // ---- prologue: stage chunk 0 ----
    {
        uint4 wA = *reinterpret_cast<const uint4*>(Wp + (size_t)wrow * KW + wcol);
        uint4 wB = *reinterpret_cast<const uint4*>(Wp + ((size_t)wrow + 256) * KW + wcol);
        #pragma unroll
        for (int i = 0; i < 4; ++i) {
            float4 v = xf4[((size_t)(row0 + w * 4 + i) << 10) + l];
            xb[i][0] = __ballot(v.x < 0.f);
            xb[i][1] = __ballot(v.y < 0.f);
            xb[i][2] = __ballot(v.z < 0.f);
            xb[i][3] = __ballot(v.w < 0.f);
        }
        *reinterpret_cast<uint4*>(&sW[0][wrow][wcol]) = wA;
        *reinterpret_cast<uint4*>(&sW[0][wrow + 256][wcol]) = wB;
        __syncthreads();
    }

    for (int c = 0; c < NCH; ++c) {
        const int cb = c & 1, nb = cb ^ 1;
        const bool pf = (c + 1 < NCH);
        uint4 wA, wB;
        float4 xr[4];

        // ---- A: issue W loads (L2-hot) first, then x loads (HBM) ----
        if (pf) {
            const uint32_t* wsrc = Wp + (c + 1) * KC;
            wA = *reinterpret_cast<const uint4*>(wsrc + (size_t)wrow * KW + wcol);
            wB = *reinterpret_cast<const uint4*>(wsrc + ((size_t)wrow + 256) * KW + wcol);
            #pragma unroll
            for (int i = 0; i < 4; ++i)
                xr[i] = xf4[((size_t)(row0 + w * 4 + i) << 10) + (size_t)(c + 1) * 64 + l];
        }

        // ---- B: popcount-GEMM chunk c (x from SGPRs, W from LDS b128) ----
        #pragma unroll
        for (int j2 = 0; j2 < 4; ++j2) {
            const int u0 = l + 128 * j2;
            uint4 w0a = *reinterpret_cast<const uint4*>(&sW[cb][u0][0]);
            uint4 w0b = *reinterpret_cast<const uint4*>(&sW[cb][u0][4]);
            uint4 w1a = *reinterpret_cast<const uint4*>(&sW[cb][u0 + 64][0]);
            uint4 w1b = *reinterpret_cast<const uint4*>(&sW[cb][u0 + 64][4]);
            #pragma unroll
            for (int i = 0; i < 4; ++i) {
                uint32_t x0 = (uint32_t)xb[i][0], x1 = (uint32_t)(xb[i][0] >> 32);
                uint32_t x2 = (uint32_t)xb[i][1], x3 = (uint32_t)(xb[i][1] >> 32);
                uint32_t x4 = (uint32_t)xb[i][2], x5 = (uint32_t)(xb[i][2] >> 32);
                uint32_t x6 = (uint32_t)xb[i][3], x7 = (uint32_t)(xb[i][3] >> 32);
                uint32_t c0 = __popc(x0 ^ w0a.x) + __popc(x1 ^ w0a.y)
                            + __popc(x2 ^ w0a.z) + __popc(x3 ^ w0a.w)
                            + __popc(x4 ^ w0b.x) + __popc(x5 ^ w0b.y)
                            + __popc(x6 ^ w0b.z) + __popc(x7 ^ w0b.w);
                uint32_t c1 = __popc(x0 ^ w1a.x) + __popc(x1 ^ w1a.y)
                            + __popc(x2 ^ w1a.z) + __popc(x3 ^ w1a.w)
                            + __popc(x4 ^ w1b.x) + __popc(x5 ^ w1b.y)
                            + __popc(x6 ^ w1b.z) + __popc(x7 ^ w1b.w);
                acc[i][j2] += c0 + (c1 << 16);
            }
        }

        // ---- C: commit W to sW[nb]; ballot-pack next x into SGPRs ----
        if (pf) {
            *reinterpret_cast<uint4*>(&sW[nb][wrow][wcol]) = wA;
            *reinterpret_cast<uint4*>(&sW[nb][wrow + 256][wcol]) = wB;
            #pragma unroll
            for (int i = 0; i < 4; ++i) {
                xb[i][0] = __ballot(xr[i].x < 0.f);
                xb[i][1] = __ballot(xr[i].y < 0.f);
                xb[i][2] = __ballot(xr[i].z < 0.f);
                xb[i][3] = __ballot(xr[i].w < 0.f);
            }
        }
        __syncthreads();
    }

    // ---- epilogue: unpack u16 halves, C = INF - 2*acc + bias ----
    #pragma unroll
    for (int j2 = 0; j2 < 4; ++j2) {
        const int u0 = l + 128 * j2, u1 = u0 + 64;
        const float bv0 = bias[u0], bv1 = bias[u1];
        #pragma unroll
        for (int i = 0; i < 4; ++i) {
            size_t r = (size_t)(row0 + w * 4 + i) * UNITS;
            uint32_t pk = acc[i][j2];
            C[r + u0] = (float)(INF - 2 * (int)(pk & 0xFFFFu)) + bv0;
            C[r + u1] = (float)(INF - 2 * (int)(pk >> 16)) + bv1;
        }
    }
}

extern "C" void kernel_launch(void* const* d_in, const int* in_sizes, int n_in,
                              void* d_out, int out_size, void* d_ws, size_t ws_size,
                              hipStream_t stream) {
    const float* x = (const float*)d_in[0];
    const float* W = (const float*)d_in[1];
    const float* b = (const float*)d_in[2];
    float* out = (float*)d_out;

    unsigned long long* Wp = (unsigned long long*)d_ws;   // 256 KB

    pack_w_kernel<<<32768 / 256, 256, 0, stream>>>(W, Wp);
    fused_kernel<<<BATCH / ROWSB, 512, 0, stream>>>(
        x, (const uint32_t*)Wp, b, out);
}